// Round 9
// baseline (155.950 us; speedup 1.0000x reference)
//
#include <hip/hip_runtime.h>
#include <hip/hip_bf16.h>

#define D 128
#define MARGIN 0.5f
#define JW 256          // j-window per block (8 phases of 32)
#define NWIN 32         // n / JW i-side slab count
#define NBI 64          // i-blocks of 128 rows; transpose slab count

typedef __attribute__((ext_vector_type(8))) short bf16x8;
typedef __attribute__((ext_vector_type(4))) float f32x4;

// ---------------- prep: bf16 convert + sq + slab/out init ----------------
__global__ void prep_kernel(const float* __restrict__ x,
                            float* __restrict__ sq,
                            __hip_bfloat16* __restrict__ xb,
                            float* __restrict__ pap, float* __restrict__ pan,
                            float* __restrict__ pap2, float* __restrict__ pan2,
                            float* __restrict__ out, int n) {
    int tid = threadIdx.x;
    int row = blockIdx.x * 4 + (tid >> 6);
    int lane = tid & 63;
    const float2* xr = (const float2*)(x + (size_t)row * D);
    float2 v = xr[lane];
    __hip_bfloat162 b2;
    b2.x = __float2bfloat16(v.x);
    b2.y = __float2bfloat16(v.y);
    ((__hip_bfloat162*)(xb + (size_t)row * D))[lane] = b2;
    float s = v.x * v.x + v.y * v.y;
    #pragma unroll
    for (int o = 32; o > 0; o >>= 1) s += __shfl_xor(s, o, 64);
    if (lane == 0) sq[row] = s;

    // slab init: unwritten (bi,by) triangle holes must be neutral.
    int g = blockIdx.x * 256 + tid;          // [0, 64n)
    pap2[g] = 0.0f;
    pan2[g] = 1e30f;
    if (g < n * NWIN) { pap[g] = 0.0f; pan[g] = 1e30f; }
    if (blockIdx.x == 0 && tid == 0) *out = 0.0f;
}

// ---------------- gram: triangle + REGISTER DIET (R9) ---------------------
// R8 post-mortem: fully-static indexing changed nothing vs R7 (VGPR 64,
// WRITE 105MB both) -> the spill is register-pressure overflow of the
// launch_bounds(256,4) 128-VGPR cap (105MB/270K thr ~ 12 regs re-spilled
// per phase), not runtime indexing. Diet, same algorithm & pipeline:
//  (1) jpreg/jnreg ELIMINATED: each tile's 16 j-cols are unique, so
//      post-shuffle jp/jn go straight to LDS jps/jns[wave][col] (quad-0
//      writes, conflict-free 64B) -- no register accumulation, no
//      owner-quad select. Cross-wave merge once at the end.
//  (2) siv -> LDS sis[128]: i-row sq read per tile via broadcast
//      ds_read_b32 (4 distinct addrs/instr, conflict-free).
//  (3) ring 4->3 slots (24KB) so LDS = 24+8+2.5KB fits 4 blocks/CU;
//      prefetch depth 2, steady-state s_waitcnt vmcnt(2) (never 0 mid-loop).
// Persistent regs: afrag 32 + li 8 + lap/lan 16 = 56 (+transients) < 128.
// Algorithm (R8-verified, absmax 0): blocks (bi 0..63, by >= bi/2) = 1056;
// each pair computed once updates row i (lap/lan -> pap[by]) and row j
// (jp/jn -> pap2[bi]); duplicates idempotent; triangle holes neutral-init.
__launch_bounds__(256, 4)
__global__ void gram_kernel(const __hip_bfloat16* __restrict__ xb,
                            const float* __restrict__ sq,
                            const int* __restrict__ tgt,
                            float* __restrict__ pap,
                            float* __restrict__ pan,
                            float* __restrict__ pap2,
                            float* __restrict__ pan2, int n) {
    __shared__ __align__(16) __hip_bfloat16 Bs[3][32 * D];  // 3 x 8KB ring
    __shared__ float sqs[JW];
    __shared__ int   tgs[JW];
    __shared__ float sis[128];
    __shared__ float jps[4][JW];
    __shared__ float jns[4][JW];

    const int tid  = threadIdx.x;
    const int wid  = tid >> 6;
    const int lane = tid & 63;
    const int quad = lane >> 4;
    const int l    = lane & 15;

    // bid -> (bi, by) triangle mapping (by >= bi/2); <=64 scalar iters
    int bi = 0, rem = blockIdx.x;
    while (rem >= NWIN - (bi >> 1)) { rem -= NWIN - (bi >> 1); ++bi; }
    const int by = (bi >> 1) + rem;

    const int i0 = bi * 128;
    const int j0 = by * JW;
    const int rowbase = i0 + wid * 32;

    // metadata first (their ds_writes' implicit vmcnt waits drain only
    // these loads, not the prefetches issued below)
    sqs[tid] = sq[j0 + tid];
    tgs[tid] = tgt[j0 + tid];
    if (tid < 128) sis[tid] = sq[i0 + tid];

    // A fragments, register-resident: lane holds A[m=l][k=quad*8+r]
    bf16x8 afrag[2][4];
    {
        const __hip_bfloat16* abase = xb + (size_t)(rowbase + l) * D + quad * 8;
        #pragma unroll
        for (int mt = 0; mt < 2; ++mt)
            #pragma unroll
            for (int ks = 0; ks < 4; ++ks)
                afrag[mt][ks] = *(const bf16x8*)(abase + (size_t)mt * 16 * D + ks * 32);
    }

    int li[2][4];
    #pragma unroll
    for (int mt = 0; mt < 2; ++mt)
        #pragma unroll
        for (int reg = 0; reg < 4; ++reg)
            li[mt][reg] = tgt[rowbase + mt * 16 + quad * 4 + reg];

    float lap[8], lan[8];
    #pragma unroll
    for (int k = 0; k < 8; ++k) { lap[k] = -1e30f; lan[k] = 1e30f; }

    const char* xbb = (const char*)xb;

    #define PREF_HALF(h, s)                                                   \
        do {                                                                  \
            _Pragma("unroll")                                                 \
            for (int i_ = 0; i_ < 2; ++i_) {                                  \
                int q_ = wid * 128 + i_ * 64 + lane;                          \
                int r_ = q_ >> 4;                                             \
                int c_ = (q_ & 15) ^ (r_ & 15);                               \
                const char* g_ = xbb + (size_t)(j0 + (h) * 32 + r_) * 256     \
                                     + (size_t)c_ * 16;                       \
                char* l_ = (char*)Bs + (size_t)(s) * 8192                     \
                         + (size_t)(wid * 128 + i_ * 64) * 16;                \
                __builtin_amdgcn_global_load_lds(                             \
                    (const __attribute__((address_space(1))) void*)g_,        \
                    (__attribute__((address_space(3))) void*)l_, 16, 0, 0);   \
            }                                                                 \
        } while (0)

    // ONE 16x16x32 j-tile; literal (h, jt, s). j-side partials go straight
    // to LDS (unique cols per tile) -- zero persistent j-side registers.
    #define COMP_TILE(h, jt, s)                                               \
        do {                                                                  \
            const char* Bb_ = (const char*)Bs + (size_t)(s) * 8192;           \
            f32x4 acc0 = (f32x4){0.f, 0.f, 0.f, 0.f};                         \
            f32x4 acc1 = (f32x4){0.f, 0.f, 0.f, 0.f};                         \
            __builtin_amdgcn_s_setprio(1);                                    \
            _Pragma("unroll")                                                 \
            for (int ks = 0; ks < 4; ++ks) {                                  \
                int q = ((jt) * 16 + l) * 16 + ((ks * 4 + quad) ^ l);         \
                bf16x8 bfr = *(const bf16x8*)(Bb_ + (size_t)q * 16);          \
                acc0 = __builtin_amdgcn_mfma_f32_16x16x32_bf16(               \
                    afrag[0][ks], bfr, acc0, 0, 0, 0);                        \
                acc1 = __builtin_amdgcn_mfma_f32_16x16x32_bf16(               \
                    afrag[1][ks], bfr, acc1, 0, 0, 0);                        \
            }                                                                 \
            __builtin_amdgcn_s_setprio(0);                                    \
            float sjc = sqs[(h) * 32 + (jt) * 16 + l];                        \
            int   tjc = tgs[(h) * 32 + (jt) * 16 + l];                        \
            float jp = -1e30f, jn = 1e30f;                                    \
            _Pragma("unroll")                                                 \
            for (int reg = 0; reg < 4; ++reg) {                               \
                float si0 = sis[wid * 32 + quad * 4 + reg];                   \
                float si1 = sis[wid * 32 + 16 + quad * 4 + reg];              \
                float a0 = acc0[reg], a1 = acc1[reg];                         \
                float t0 = fmaf(-2.0f, a0, sjc);                              \
                float t1 = fmaf(-2.0f, a1, sjc);                              \
                float u0 = fmaf(-2.0f, a0, si0);                              \
                float u1 = fmaf(-2.0f, a1, si1);                              \
                bool s0 = (li[0][reg] == tjc);                                \
                bool s1 = (li[1][reg] == tjc);                                \
                lap[reg]     = fmaxf(lap[reg],     s0 ? t0 : -1e30f);         \
                lan[reg]     = fminf(lan[reg],     s0 ? 1e30f : t0);          \
                lap[4 + reg] = fmaxf(lap[4 + reg], s1 ? t1 : -1e30f);         \
                lan[4 + reg] = fminf(lan[4 + reg], s1 ? 1e30f : t1);          \
                jp = fmaxf(jp, s0 ? u0 : -1e30f);                             \
                jp = fmaxf(jp, s1 ? u1 : -1e30f);                             \
                jn = fminf(jn, s0 ? 1e30f : u0);                              \
                jn = fminf(jn, s1 ? 1e30f : u1);                              \
            }                                                                 \
            jp = fmaxf(jp, __shfl_xor(jp, 16, 64));                           \
            jp = fmaxf(jp, __shfl_xor(jp, 32, 64));                           \
            jn = fminf(jn, __shfl_xor(jn, 16, 64));                           \
            jn = fminf(jn, __shfl_xor(jn, 32, 64));                           \
            if (quad == 0) {                                                  \
                jps[wid][(h) * 32 + (jt) * 16 + l] = jp;                      \
                jns[wid][(h) * 32 + (jt) * 16 + l] = jn;                      \
            }                                                                 \
        } while (0)

    #define WAITBAR(N)                                                        \
        asm volatile("s_waitcnt vmcnt(" #N ")" ::: "memory");                 \
        __builtin_amdgcn_s_barrier();                                         \
        asm volatile("" ::: "memory")

    // prologue: 2 tiles in flight (4 glds/wave)
    PREF_HALF(0, 0);
    PREF_HALF(1, 1);
    asm volatile("s_waitcnt lgkmcnt(0)" ::: "memory");

    // 8 phases, fully static; slots h%3; steady-state vmcnt(2)
    WAITBAR(2); PREF_HALF(2, 2); COMP_TILE(0, 0, 0); COMP_TILE(0, 1, 0);
    WAITBAR(2); PREF_HALF(3, 0); COMP_TILE(1, 0, 1); COMP_TILE(1, 1, 1);
    WAITBAR(2); PREF_HALF(4, 1); COMP_TILE(2, 0, 2); COMP_TILE(2, 1, 2);
    WAITBAR(2); PREF_HALF(5, 2); COMP_TILE(3, 0, 0); COMP_TILE(3, 1, 0);
    WAITBAR(2); PREF_HALF(6, 0); COMP_TILE(4, 0, 1); COMP_TILE(4, 1, 1);
    WAITBAR(2); PREF_HALF(7, 1); COMP_TILE(5, 0, 2); COMP_TILE(5, 1, 2);
    WAITBAR(2);                  COMP_TILE(6, 0, 0); COMP_TILE(6, 1, 0);
    WAITBAR(0);                  COMP_TILE(7, 0, 1); COMP_TILE(7, 1, 1);

    #undef PREF_HALF
    #undef COMP_TILE
    #undef WAITBAR

    // i-side: reduce across 16 column-lanes, store to slab by
    #pragma unroll
    for (int mt = 0; mt < 2; ++mt)
        #pragma unroll
        for (int reg = 0; reg < 4; ++reg) {
            float p = lap[mt * 4 + reg], q = lan[mt * 4 + reg];
            #pragma unroll
            for (int o = 1; o < 16; o <<= 1) {
                p = fmaxf(p, __shfl_xor(p, o, 64));
                q = fminf(q, __shfl_xor(q, o, 64));
            }
            if (l == mt * 4 + reg) {
                int gi = rowbase + mt * 16 + quad * 4 + reg;
                float s = sis[wid * 32 + mt * 16 + quad * 4 + reg];
                pap[(size_t)by * n + gi] = fmaxf(s + p, 0.0f);
                pan[(size_t)by * n + gi] = fmaxf(s + q, 0.0f);
            }
        }

    // j-side: cross-wave merge of jps/jns, store to transpose slab bi
    __syncthreads();
    {
        int w = tid;                          // 256 threads, 1 col each
        float p2 = fmaxf(fmaxf(jps[0][w], jps[1][w]),
                         fmaxf(jps[2][w], jps[3][w]));
        float n2 = fminf(fminf(jns[0][w], jns[1][w]),
                         fminf(jns[2][w], jns[3][w]));
        float sj = sqs[w];
        pap2[(size_t)bi * n + j0 + w] = fmaxf(sj + p2, 0.0f);
        pan2[(size_t)bi * n + j0 + w] = fmaxf(sj + n2, 0.0f);
    }
}

// ---------------- final: reduce 32+64 slabs, sum relu(ap - an + margin) ---
__global__ void final_kernel(const float* __restrict__ pap,
                             const float* __restrict__ pan,
                             const float* __restrict__ pap2,
                             const float* __restrict__ pan2,
                             float* __restrict__ out, int n) {
    int i = blockIdx.x * blockDim.x + threadIdx.x;
    float p = pap[i], q = pan[i];
    #pragma unroll 4
    for (int s = 1; s < NWIN; ++s) {
        p = fmaxf(p, pap[(size_t)s * n + i]);
        q = fminf(q, pan[(size_t)s * n + i]);
    }
    #pragma unroll 4
    for (int b = 0; b < NBI; ++b) {
        p = fmaxf(p, pap2[(size_t)b * n + i]);
        q = fminf(q, pan2[(size_t)b * n + i]);
    }
    float v = fmaxf(p - q + MARGIN, 0.0f);
    #pragma unroll
    for (int o = 32; o > 0; o >>= 1) v += __shfl_xor(v, o, 64);
    __shared__ float ws[4];
    int lane = threadIdx.x & 63, w = threadIdx.x >> 6;
    if (lane == 0) ws[w] = v;
    __syncthreads();
    if (threadIdx.x == 0) atomicAdd(out, ws[0] + ws[1] + ws[2] + ws[3]);
}

extern "C" void kernel_launch(void* const* d_in, const int* in_sizes, int n_in,
                              void* d_out, int out_size, void* d_ws, size_t ws_size,
                              hipStream_t stream) {
    const float* x   = (const float*)d_in[0];
    const int*   tgt = (const int*)d_in[1];
    float* out = (float*)d_out;
    const int n = in_sizes[1];              // 8192

    // ws: sq | pap[NWIN*n] | pan[NWIN*n] | pap2[NBI*n] | pan2[NBI*n] | xb
    float* sq   = (float*)d_ws;
    float* pap  = sq + n;
    float* pan  = pap + (size_t)NWIN * n;
    float* pap2 = pan + (size_t)NWIN * n;
    float* pan2 = pap2 + (size_t)NBI * n;
    __hip_bfloat16* xb = (__hip_bfloat16*)(pan2 + (size_t)NBI * n);

    int nblk = 0;
    for (int b = 0; b < NBI; ++b) nblk += NWIN - (b >> 1);   // 1056

    prep_kernel<<<n / 4, 256, 0, stream>>>(x, sq, xb, pap, pan, pap2, pan2, out, n);
    gram_kernel<<<nblk, 256, 0, stream>>>(xb, sq, tgt, pap, pan, pap2, pan2, n);
    final_kernel<<<n / 256, 256, 0, stream>>>(pap, pan, pap2, pan2, out, n);
}

// Round 10
// 100.599 us; speedup vs baseline: 1.5502x; 1.5502x over previous
//
#include <hip/hip_runtime.h>
#include <hip/hip_bf16.h>

#define D 128
#define MARGIN 0.5f
#define JW 256          // j-window per block (8 phases of 32)
#define NWIN 32         // n / JW i-side slab count
#define NBI 64          // i-blocks of 128 rows; transpose slab count

typedef __attribute__((ext_vector_type(8))) short bf16x8;
typedef __attribute__((ext_vector_type(4))) float f32x4;

// ---------------- prep: bf16 convert + sq + slab/out init ----------------
__global__ void prep_kernel(const float* __restrict__ x,
                            float* __restrict__ sq,
                            __hip_bfloat16* __restrict__ xb,
                            float* __restrict__ pap, float* __restrict__ pan,
                            float* __restrict__ pap2, float* __restrict__ pan2,
                            float* __restrict__ out, int n) {
    int tid = threadIdx.x;
    int row = blockIdx.x * 4 + (tid >> 6);
    int lane = tid & 63;
    const float2* xr = (const float2*)(x + (size_t)row * D);
    float2 v = xr[lane];
    __hip_bfloat162 b2;
    b2.x = __float2bfloat16(v.x);
    b2.y = __float2bfloat16(v.y);
    ((__hip_bfloat162*)(xb + (size_t)row * D))[lane] = b2;
    float s = v.x * v.x + v.y * v.y;
    #pragma unroll
    for (int o = 32; o > 0; o >>= 1) s += __shfl_xor(s, o, 64);
    if (lane == 0) sq[row] = s;

    // slab init: unwritten (bi,by) triangle holes must be neutral.
    int g = blockIdx.x * 256 + tid;          // [0, 64n)
    pap2[g] = 0.0f;
    pan2[g] = 1e30f;
    if (g < n * NWIN) { pap[g] = 0.0f; pan[g] = 1e30f; }
    if (blockIdx.x == 0 && tid == 0) *out = 0.0f;
}

// ---------------- gram: triangle + PLAIN __syncthreads pipeline (R10) -----
// R9 post-mortem: the spill (~99MB scratch round-trip, invariant under two
// register diets) tracks the INLINE-ASM phase machinery, not named values:
// R5 (same asm pipeline, i-side only) and R4 (no asm) had WRITE ~1KB, while
// all three asm-expanded triangle versions spill identically. The 8x
// asm-"memory"-clobber expansion splits live ranges until the allocator
// spills ~11 dwords/phase. R1-vs-R2 measured the counted-vmcnt machinery's
// whole value at <=2us -- not worth 60us of scratch. So: triangle algorithm
// (HW-verified absmax=0 in R7-R9) + the SIMPLE verified R1 pipeline: plain
// double-buffer, PREFETCH(h+1) -> COMP(h) -> __syncthreads(). No inline
// asm, no setprio, no launch-bounds pin. Runtime h indexes only LDS
// pointers, never register arrays (rule #20 safe; R1 proved clean).
// Algorithm: blocks (bi 0..63, by >= bi/2) = 1056; each pair computed once
// updates row i (lap/lan -> pap[by] slab) and row j (jp/jn -> LDS -> 
// pap2[bi] slab); duplicates idempotent; triangle holes neutral-init.
// LDS: Bs 2x8KB dbuf + jps/jns 8KB + meta 2.5KB = 26.5KB -> 5 blocks/CU.
__launch_bounds__(256)
__global__ void gram_kernel(const __hip_bfloat16* __restrict__ xb,
                            const float* __restrict__ sq,
                            const int* __restrict__ tgt,
                            float* __restrict__ pap,
                            float* __restrict__ pan,
                            float* __restrict__ pap2,
                            float* __restrict__ pan2, int n) {
    __shared__ __align__(16) __hip_bfloat16 Bs[2][32 * D];  // 2 x 8KB dbuf
    __shared__ float sqs[JW];
    __shared__ int   tgs[JW];
    __shared__ float sis[128];
    __shared__ float jps[4][JW];
    __shared__ float jns[4][JW];

    const int tid  = threadIdx.x;
    const int wid  = tid >> 6;
    const int lane = tid & 63;
    const int quad = lane >> 4;
    const int l    = lane & 15;

    // bid -> (bi, by) triangle mapping (by >= bi/2); <=64 scalar iters
    int bi = 0, rem = blockIdx.x;
    while (rem >= NWIN - (bi >> 1)) { rem -= NWIN - (bi >> 1); ++bi; }
    const int by = (bi >> 1) + rem;

    const int i0 = bi * 128;
    const int j0 = by * JW;
    const int rowbase = i0 + wid * 32;

    // metadata stage (coalesced)
    sqs[tid] = sq[j0 + tid];
    tgs[tid] = tgt[j0 + tid];
    if (tid < 128) sis[tid] = sq[i0 + tid];

    // A fragments, register-resident: lane holds A[m=l][k=quad*8+r]
    bf16x8 afrag[2][4];
    {
        const __hip_bfloat16* abase = xb + (size_t)(rowbase + l) * D + quad * 8;
        #pragma unroll
        for (int mt = 0; mt < 2; ++mt)
            #pragma unroll
            for (int ks = 0; ks < 4; ++ks)
                afrag[mt][ks] = *(const bf16x8*)(abase + (size_t)mt * 16 * D + ks * 32);
    }

    int li[2][4];
    #pragma unroll
    for (int mt = 0; mt < 2; ++mt)
        #pragma unroll
        for (int reg = 0; reg < 4; ++reg)
            li[mt][reg] = tgt[rowbase + mt * 16 + quad * 4 + reg];

    float lap[8], lan[8];
    #pragma unroll
    for (int k = 0; k < 8; ++k) { lap[k] = -1e30f; lan[k] = 1e30f; }

    // staging: half-tile (32 rows = 512 chunks of 16B), wave wid owns
    // chunks q = wid*128 + i*64 + lane. LDS chunk q holds global
    // (row r=q>>4, chunk c=(q&15)^(r&15)) of the half-tile (XOR swizzle on
    // the GLOBAL src addr; LDS dest wave-uniform base + lane*16).
    const char* xbb = (const char*)xb;

    #define PREF_HALF(h, buf)                                                 \
        do {                                                                  \
            _Pragma("unroll")                                                 \
            for (int i_ = 0; i_ < 2; ++i_) {                                  \
                int q_ = wid * 128 + i_ * 64 + lane;                          \
                int r_ = q_ >> 4;                                             \
                int c_ = (q_ & 15) ^ (r_ & 15);                               \
                const char* g_ = xbb + (size_t)(j0 + (h) * 32 + r_) * 256     \
                                     + (size_t)c_ * 16;                       \
                char* l_ = (char*)Bs + (size_t)(buf) * 8192                   \
                         + (size_t)(wid * 128 + i_ * 64) * 16;                \
                __builtin_amdgcn_global_load_lds(                             \
                    (const __attribute__((address_space(1))) void*)g_,        \
                    (__attribute__((address_space(3))) void*)l_, 16, 0, 0);   \
            }                                                                 \
        } while (0)

    PREF_HALF(0, 0);
    __syncthreads();   // drains vmcnt -> tile 0 resident; metadata visible

    for (int h = 0; h < 8; ++h) {
        const int cur = h & 1;
        if (h < 7) PREF_HALF(h + 1, cur ^ 1);   // async into other buffer

        const char* Bb = (const char*)Bs + (size_t)cur * 8192;
        #pragma unroll
        for (int jt = 0; jt < 2; ++jt) {
            f32x4 acc0 = (f32x4){0.f, 0.f, 0.f, 0.f};
            f32x4 acc1 = (f32x4){0.f, 0.f, 0.f, 0.f};
            #pragma unroll
            for (int ks = 0; ks < 4; ++ks) {
                // frag: row jt*16+l, k-chunk (ks*4+quad) ^ l (swizzled)
                int q = (jt * 16 + l) * 16 + ((ks * 4 + quad) ^ l);
                bf16x8 bfr = *(const bf16x8*)(Bb + (size_t)q * 16);
                acc0 = __builtin_amdgcn_mfma_f32_16x16x32_bf16(
                    afrag[0][ks], bfr, acc0, 0, 0, 0);
                acc1 = __builtin_amdgcn_mfma_f32_16x16x32_bf16(
                    afrag[1][ks], bfr, acc1, 0, 0, 0);
            }
            const int jcol = h * 32 + jt * 16 + l;
            float sjc = sqs[jcol];
            int   tjc = tgs[jcol];
            float jp = -1e30f, jn = 1e30f;
            #pragma unroll
            for (int reg = 0; reg < 4; ++reg) {
                float si0 = sis[wid * 32 + quad * 4 + reg];
                float si1 = sis[wid * 32 + 16 + quad * 4 + reg];
                float a0 = acc0[reg], a1 = acc1[reg];
                float t0 = fmaf(-2.0f, a0, sjc);
                float t1 = fmaf(-2.0f, a1, sjc);
                float u0 = fmaf(-2.0f, a0, si0);
                float u1 = fmaf(-2.0f, a1, si1);
                bool s0 = (li[0][reg] == tjc);
                bool s1 = (li[1][reg] == tjc);
                lap[reg]     = fmaxf(lap[reg],     s0 ? t0 : -1e30f);
                lan[reg]     = fminf(lan[reg],     s0 ? 1e30f : t0);
                lap[4 + reg] = fmaxf(lap[4 + reg], s1 ? t1 : -1e30f);
                lan[4 + reg] = fminf(lan[4 + reg], s1 ? 1e30f : t1);
                jp = fmaxf(jp, s0 ? u0 : -1e30f);
                jp = fmaxf(jp, s1 ? u1 : -1e30f);
                jn = fminf(jn, s0 ? 1e30f : u0);
                jn = fminf(jn, s1 ? 1e30f : u1);
            }
            // j-side: reduce the wave's 32 i-rows (cross-quad), park in LDS
            jp = fmaxf(jp, __shfl_xor(jp, 16, 64));
            jp = fmaxf(jp, __shfl_xor(jp, 32, 64));
            jn = fminf(jn, __shfl_xor(jn, 16, 64));
            jn = fminf(jn, __shfl_xor(jn, 32, 64));
            if (quad == 0) {
                jps[wid][jcol] = jp;
                jns[wid][jcol] = jn;
            }
        }

        // barrier: (a) drains this iter's prefetch before next compute,
        // (b) all waves done reading Bs[cur] before it's overwritten.
        __syncthreads();
    }
    #undef PREF_HALF

    // i-side: reduce across 16 column-lanes, store to slab by
    #pragma unroll
    for (int mt = 0; mt < 2; ++mt)
        #pragma unroll
        for (int reg = 0; reg < 4; ++reg) {
            float p = lap[mt * 4 + reg], q = lan[mt * 4 + reg];
            #pragma unroll
            for (int o = 1; o < 16; o <<= 1) {
                p = fmaxf(p, __shfl_xor(p, o, 64));
                q = fminf(q, __shfl_xor(q, o, 64));
            }
            if (l == mt * 4 + reg) {
                int gi = rowbase + mt * 16 + quad * 4 + reg;
                float s = sis[wid * 32 + mt * 16 + quad * 4 + reg];
                pap[(size_t)by * n + gi] = fmaxf(s + p, 0.0f);
                pan[(size_t)by * n + gi] = fmaxf(s + q, 0.0f);
            }
        }

    // j-side: cross-wave merge of jps/jns, store to transpose slab bi
    // (last loop iteration ended with __syncthreads -> jps/jns complete)
    {
        int w = tid;                          // 256 threads, 1 col each
        float p2 = fmaxf(fmaxf(jps[0][w], jps[1][w]),
                         fmaxf(jps[2][w], jps[3][w]));
        float n2 = fminf(fminf(jns[0][w], jns[1][w]),
                         fminf(jns[2][w], jns[3][w]));
        float sj = sqs[w];
        pap2[(size_t)bi * n + j0 + w] = fmaxf(sj + p2, 0.0f);
        pan2[(size_t)bi * n + j0 + w] = fmaxf(sj + n2, 0.0f);
    }
}

// ---------------- final: reduce 32+64 slabs, sum relu(ap - an + margin) ---
__global__ void final_kernel(const float* __restrict__ pap,
                             const float* __restrict__ pan,
                             const float* __restrict__ pap2,
                             const float* __restrict__ pan2,
                             float* __restrict__ out, int n) {
    int i = blockIdx.x * blockDim.x + threadIdx.x;
    float p = pap[i], q = pan[i];
    #pragma unroll 4
    for (int s = 1; s < NWIN; ++s) {
        p = fmaxf(p, pap[(size_t)s * n + i]);
        q = fminf(q, pan[(size_t)s * n + i]);
    }
    #pragma unroll 4
    for (int b = 0; b < NBI; ++b) {
        p = fmaxf(p, pap2[(size_t)b * n + i]);
        q = fminf(q, pan2[(size_t)b * n + i]);
    }
    float v = fmaxf(p - q + MARGIN, 0.0f);
    #pragma unroll
    for (int o = 32; o > 0; o >>= 1) v += __shfl_xor(v, o, 64);
    __shared__ float ws[4];
    int lane = threadIdx.x & 63, w = threadIdx.x >> 6;
    if (lane == 0) ws[w] = v;
    __syncthreads();
    if (threadIdx.x == 0) atomicAdd(out, ws[0] + ws[1] + ws[2] + ws[3]);
}

extern "C" void kernel_launch(void* const* d_in, const int* in_sizes, int n_in,
                              void* d_out, int out_size, void* d_ws, size_t ws_size,
                              hipStream_t stream) {
    const float* x   = (const float*)d_in[0];
    const int*   tgt = (const int*)d_in[1];
    float* out = (float*)d_out;
    const int n = in_sizes[1];              // 8192

    // ws: sq | pap[NWIN*n] | pan[NWIN*n] | pap2[NBI*n] | pan2[NBI*n] | xb
    float* sq   = (float*)d_ws;
    float* pap  = sq + n;
    float* pan  = pap + (size_t)NWIN * n;
    float* pap2 = pan + (size_t)NWIN * n;
    float* pan2 = pap2 + (size_t)NBI * n;
    __hip_bfloat16* xb = (__hip_bfloat16*)(pan2 + (size_t)NBI * n);

    int nblk = 0;
    for (int b = 0; b < NBI; ++b) nblk += NWIN - (b >> 1);   // 1056

    prep_kernel<<<n / 4, 256, 0, stream>>>(x, sq, xb, pap, pan, pap2, pan2, out, n);
    gram_kernel<<<nblk, 256, 0, stream>>>(xb, sq, tgt, pap, pan, pap2, pan2, n);
    final_kernel<<<n / 256, 256, 0, stream>>>(pap, pan, pap2, pan2, out, n);
}